// Round 1
// baseline (8758.636 us; speedup 1.0000x reference)
//
#include <hip/hip_runtime.h>
#include <math.h>

// Problem constants
#define S_    32
#define U_    10
#define B_    320           // S*U sequences
#define T_    120
#define NMEL_ 40
#define H_    768
#define G4_   3072          // 4*H gates
#define D_    256
#define XP_   64            // mel features zero-padded 40 -> 64 (multiple of 32)
#define K0_   (XP_ + H_)    // 832, layer-0 fused K
#define K12_  (2 * H_)      // 1536, layers 1/2 fused K

typedef _Float16 half8 __attribute__((ext_vector_type(8)));
typedef float floatx4 __attribute__((ext_vector_type(4)));

__device__ __forceinline__ float sigm(float x) { return 1.f / (1.f + expf(-x)); }

// ---------------- prep kernels ----------------

// mel (S,U,1,NMEL,T) -> x0 (B, T, XP) fp16, transposed + zero-padded
__global__ void prep_x0(const float* __restrict__ mel, _Float16* __restrict__ x0) {
  int idx = blockIdx.x * 256 + threadIdx.x;
  if (idx >= B_ * T_ * XP_) return;
  int k = idx & (XP_ - 1);
  int t = (idx >> 6) % T_;
  int b = idx / (XP_ * T_);
  float v = (k < NMEL_) ? mel[((size_t)b * NMEL_ + k) * T_ + t] : 0.f;
  x0[idx] = (_Float16)v;
}

// Wc0 (G4, K0) = [Wih0 | 0-pad | Whh0] fp16
__global__ void prep_w0(const float* __restrict__ Wih, const float* __restrict__ Whh,
                        _Float16* __restrict__ Wc) {
  int idx = blockIdx.x * 256 + threadIdx.x;
  if (idx >= G4_ * K0_) return;
  int k = idx % K0_;
  int n = idx / K0_;
  float v = 0.f;
  if (k < NMEL_)      v = Wih[(size_t)n * NMEL_ + k];
  else if (k >= XP_)  v = Whh[(size_t)n * H_ + (k - XP_)];
  Wc[idx] = (_Float16)v;
}

// Wc (G4, K12) = [Wih | Whh] fp16
__global__ void prep_w12(const float* __restrict__ Wih, const float* __restrict__ Whh,
                         _Float16* __restrict__ Wc) {
  int idx = blockIdx.x * 256 + threadIdx.x;
  if (idx >= G4_ * K12_) return;
  int k = idx % K12_;
  int n = idx / K12_;
  float v = (k < H_) ? Wih[(size_t)n * H_ + k] : Whh[(size_t)n * H_ + (k - H_)];
  Wc[idx] = (_Float16)v;
}

__global__ void prep_bias(const float* __restrict__ bih, const float* __restrict__ bhh,
                          float* __restrict__ bias) {
  int idx = blockIdx.x * 256 + threadIdx.x;
  if (idx < G4_) bias[idx] = bih[idx] + bhh[idx];
}

// ---------------- recurrent step (wavefront: layer l does t = s - l) ----------------
// grid (48 j-tiles, 3 layers), block 256 (4 waves). Wave w owns m in [80w, 80w+80).
// Each wave: acc[5 m-tiles][4 gates] of 16x16 fp32. K-chunks of 32 via mfma 16x16x32 f16.
__global__ __launch_bounds__(256)
void lstm_step(int s, const _Float16* __restrict__ x0,
               const _Float16* __restrict__ Wc0, const _Float16* __restrict__ Wc1,
               const _Float16* __restrict__ Wc2,
               const float* __restrict__ bias, float* __restrict__ cbuf,
               _Float16* __restrict__ hbuf) {
  const int layer = blockIdx.y;
  const int t = s - layer;
  if (t < 0 || t >= T_) return;
  const int pprev = (s & 1) ^ 1;   // parity of s-1
  const int pcur = s & 1;

  const _Float16* W;
  const _Float16* xsrc;
  int K, xK;
  size_t xstride;
  if (layer == 0) {
    W = Wc0; K = K0_; xK = XP_;
    xsrc = x0 + (size_t)t * XP_; xstride = (size_t)T_ * XP_;
  } else if (layer == 1) {
    W = Wc1; K = K12_; xK = H_;
    xsrc = hbuf + (size_t)(0 * 2 + pprev) * B_ * H_; xstride = H_;
  } else {
    W = Wc2; K = K12_; xK = H_;
    xsrc = hbuf + (size_t)(1 * 2 + pprev) * B_ * H_; xstride = H_;
  }
  const float* bl = bias + layer * G4_;
  const _Float16* hown = hbuf + (size_t)(layer * 2 + pprev) * B_ * H_;
  _Float16* hout = hbuf + (size_t)(layer * 2 + pcur) * B_ * H_;
  float* cl = cbuf + (size_t)layer * B_ * H_;

  const int lane = threadIdx.x & 63;
  const int wv = threadIdx.x >> 6;
  const int lr = lane & 15;
  const int quad = lane >> 4;
  const int j = blockIdx.x * 16 + lr;   // gate unit column
  const int mwb = wv * 80;

  floatx4 acc[5][4] = {};

  for (int kc = 0; kc < K; kc += 32) {
    const int k = kc + quad * 8;
    // B fragments: W rows g*H + j, 8 contiguous k
    half8 bf[4];
#pragma unroll
    for (int g = 0; g < 4; g++)
      bf[g] = *(const half8*)(W + (size_t)(g * H_ + j) * K + k);
    // A fragments: input rows m, 8 contiguous k (x-part or own-h part; chunk-uniform)
    const bool inx = (kc < xK);
    const _Float16* abase = inx ? (xsrc + k) : (hown + (k - xK));
    const size_t astr = inx ? xstride : (size_t)H_;
    half8 af[5];
#pragma unroll
    for (int mt = 0; mt < 5; mt++)
      af[mt] = *(const half8*)(abase + (size_t)(mwb + mt * 16 + lr) * astr);
#pragma unroll
    for (int mt = 0; mt < 5; mt++)
#pragma unroll
      for (int g = 0; g < 4; g++)
        acc[mt][g] = __builtin_amdgcn_mfma_f32_16x16x32_f16(af[mt], bf[g], acc[mt][g], 0, 0, 0);
  }

  // epilogue: LSTM cell update. D layout: col = lane&15 (=j), row = quad*4 + r (=m offset)
  const float bi = bl[j], bfv = bl[H_ + j], bg = bl[2 * H_ + j], bo = bl[3 * H_ + j];
#pragma unroll
  for (int mt = 0; mt < 5; mt++) {
#pragma unroll
    for (int r = 0; r < 4; r++) {
      const int m = mwb + mt * 16 + quad * 4 + r;
      const size_t cidx = (size_t)m * H_ + j;
      float iv = acc[mt][0][r] + bi;
      float fv = acc[mt][1][r] + bfv;
      float gv = acc[mt][2][r] + bg;
      float ov = acc[mt][3][r] + bo;
      float cn = sigm(fv) * cl[cidx] + sigm(iv) * tanhf(gv);
      cl[cidx] = cn;
      hout[cidx] = (_Float16)(sigm(ov) * tanhf(cn));
    }
  }
}

// ---------------- projection + normalize ----------------
__global__ void dvec_kernel(const _Float16* __restrict__ hlast, const float* __restrict__ Wproj,
                            const float* __restrict__ bproj, float* __restrict__ d3) {
  const int m = blockIdx.x;
  const int d = threadIdx.x;
  const _Float16* h = hlast + (size_t)m * H_;
  const float* w = Wproj + (size_t)d * H_;
  float acc = bproj[d];
  for (int k = 0; k < H_; k++) acc += (float)h[k] * w[k];
  __shared__ float red[256];
  red[d] = acc * acc;
  __syncthreads();
  for (int off = 128; off > 0; off >>= 1) {
    if (d < off) red[d] += red[d + off];
    __syncthreads();
  }
  float nrm = sqrtf(red[0]);
  d3[(size_t)m * D_ + d] = acc / nrm;
}

// ---------------- GE2E ----------------
__device__ float block_reduce_sum(float x, float* red) {
  const int d = threadIdx.x;
  red[d] = x;
  __syncthreads();
  for (int off = 128; off > 0; off >>= 1) {
    if (d < off) red[d] += red[d + off];
    __syncthreads();
  }
  float r = red[0];
  __syncthreads();
  return r;
}

__global__ void cent_kernel(const float* __restrict__ d3, float* __restrict__ cent,
                            float* __restrict__ ncent) {
  const int sIdx = blockIdx.x;
  const int d = threadIdx.x;
  float acc = 0.f;
  for (int u = 0; u < U_; u++) acc += d3[((size_t)sIdx * U_ + u) * D_ + d];
  acc *= (1.f / U_);
  cent[sIdx * D_ + d] = acc;
  __shared__ float red[256];
  float n2 = block_reduce_sum(acc * acc, red);
  if (d == 0) ncent[sIdx] = fmaxf(sqrtf(n2), 1e-8f);
}

__global__ void ge2e_kernel(const float* __restrict__ d3, const float* __restrict__ cent,
                            const float* __restrict__ ncent, const float* __restrict__ loss_w,
                            const float* __restrict__ loss_b, float* __restrict__ accums) {
  const int p = blockIdx.x;      // (s,u) pair
  const int sIdx = p / U_;
  const int d = threadIdx.x;
  __shared__ float red[256];
  __shared__ float sims[S_];

  const float v = d3[(size_t)p * D_ + d];
  const float cs = cent[sIdx * D_ + d];
  const float pc = (cs * U_ - v) * (1.f / (U_ - 1));

  float nv2 = block_reduce_sum(v * v, red);
  float npc2 = block_reduce_sum(pc * pc, red);
  float dotp = block_reduce_sum(v * pc, red);

  const float w = loss_w[0], b = loss_b[0];
  const float na = fmaxf(sqrtf(nv2), 1e-6f);
  const float npc = fmaxf(sqrtf(npc2), 1e-6f);
  const float pos_sim = w * (dotp / (na * npc)) + b;
  const float nd = fmaxf(sqrtf(nv2), 1e-8f);

  for (int k = 0; k < S_; k++) {
    float dk = block_reduce_sum(v * cent[k * D_ + d], red);
    if (d == 0) sims[k] = w * (dk / (nd * ncent[k])) + b;
  }
  __syncthreads();
  if (d == 0) {
    float mx = -1e30f;
    for (int k = 0; k < S_; k++)
      if (k != sIdx) mx = fmaxf(mx, sims[k]);
    float se = 0.f, sn = 0.f;
    for (int k = 0; k < S_; k++)
      if (k != sIdx) { se += expf(sims[k] - mx); sn += sims[k]; }
    float lse = mx + logf(se);
    atomicAdd(&accums[0], -pos_sim + lse);
    atomicAdd(&accums[1], pos_sim);
    atomicAdd(&accums[2], sn);
  }
}

__global__ void finalize_kernel(const float* __restrict__ accums, float* __restrict__ out) {
  if (threadIdx.x == 0) {
    out[0] = accums[0] / (float)(S_ * U_);
    out[1] = accums[1] / (float)(S_ * U_);
    out[2] = accums[2] / (float)(S_ * U_ * (S_ - 1));
  }
}

// ---------------- launch ----------------
extern "C" void kernel_launch(void* const* d_in, const int* in_sizes, int n_in,
                              void* d_out, int out_size, void* d_ws, size_t ws_size,
                              hipStream_t stream) {
  const float* mel = (const float*)d_in[0];
  const float* Wih[3] = {(const float*)d_in[1], (const float*)d_in[5], (const float*)d_in[9]};
  const float* Whh[3] = {(const float*)d_in[2], (const float*)d_in[6], (const float*)d_in[10]};
  const float* bih[3] = {(const float*)d_in[3], (const float*)d_in[7], (const float*)d_in[11]};
  const float* bhh[3] = {(const float*)d_in[4], (const float*)d_in[8], (const float*)d_in[12]};
  const float* Wproj = (const float*)d_in[13];
  const float* bproj = (const float*)d_in[14];
  const float* loss_w = (const float*)d_in[15];
  const float* loss_b = (const float*)d_in[16];
  float* out = (float*)d_out;

  char* ws = (char*)d_ws;
  size_t off = 0;
  auto alloc = [&](size_t bytes) -> void* {
    void* p = ws + off;
    off = (off + bytes + 255) & ~(size_t)255;
    return p;
  };
  _Float16* x0   = (_Float16*)alloc((size_t)B_ * T_ * XP_ * 2);
  _Float16* Wc0  = (_Float16*)alloc((size_t)G4_ * K0_ * 2);
  _Float16* Wc1  = (_Float16*)alloc((size_t)G4_ * K12_ * 2);
  _Float16* Wc2  = (_Float16*)alloc((size_t)G4_ * K12_ * 2);
  float*    bias = (float*)alloc((size_t)3 * G4_ * 4);
  float*    cbuf = (float*)alloc((size_t)3 * B_ * H_ * 4);
  _Float16* hbuf = (_Float16*)alloc((size_t)6 * B_ * H_ * 2);
  float*    d3   = (float*)alloc((size_t)B_ * D_ * 4);
  float*    cent = (float*)alloc((size_t)S_ * D_ * 4);
  float*    ncent = (float*)alloc((size_t)S_ * 4);
  float*    accums = (float*)alloc(64);

  // zero initial cell state, h double-buffers, loss accumulators (ws is poisoned 0xAA)
  hipMemsetAsync(cbuf, 0, (size_t)3 * B_ * H_ * 4, stream);
  hipMemsetAsync(hbuf, 0, (size_t)6 * B_ * H_ * 2, stream);
  hipMemsetAsync(accums, 0, 64, stream);

  // prep
  prep_x0<<<(B_ * T_ * XP_ + 255) / 256, 256, 0, stream>>>(mel, x0);
  prep_w0<<<(G4_ * K0_ + 255) / 256, 256, 0, stream>>>(Wih[0], Whh[0], Wc0);
  prep_w12<<<(G4_ * K12_ + 255) / 256, 256, 0, stream>>>(Wih[1], Whh[1], Wc1);
  prep_w12<<<(G4_ * K12_ + 255) / 256, 256, 0, stream>>>(Wih[2], Whh[2], Wc2);
  for (int l = 0; l < 3; l++)
    prep_bias<<<(G4_ + 255) / 256, 256, 0, stream>>>(bih[l], bhh[l], bias + l * G4_);

  // wavefront-pipelined recurrence: 122 steps, 3 layers per launch
  for (int s = 0; s < T_ + 2; s++)
    lstm_step<<<dim3(48, 3), 256, 0, stream>>>(s, x0, Wc0, Wc1, Wc2, bias, cbuf, hbuf);

  // last h of layer 2 lives at parity (121 & 1) = 1
  const _Float16* hlast = hbuf + (size_t)(2 * 2 + 1) * B_ * H_;
  dvec_kernel<<<B_, 256, 0, stream>>>(hlast, Wproj, bproj, d3);
  cent_kernel<<<S_, 256, 0, stream>>>(d3, cent, ncent);
  ge2e_kernel<<<B_, 256, 0, stream>>>(d3, cent, ncent, loss_w, loss_b, accums);
  finalize_kernel<<<1, 64, 0, stream>>>(accums, out);
}

// Round 2
// 5854.503 us; speedup vs baseline: 1.4961x; 1.4961x over previous
//
#include <hip/hip_runtime.h>
#include <math.h>

// Problem constants
#define S_    32
#define U_    10
#define B_    320           // S*U sequences
#define T_    120
#define NMEL_ 40
#define H_    768
#define G4_   3072          // 4*H gates
#define D_    256
#define XP_   64            // mel features zero-padded 40 -> 64 (multiple of 32)
#define K0_   (XP_ + H_)    // 832, layer-0 fused K
#define K12_  (2 * H_)      // 1536, layers 1/2 fused K

#define NB0   48            // layer-0 blocks (16 units each)
#define NB12  96            // layer-1/2 blocks (8 units each)
#define NBLK  (NB0 + 2 * NB12)  // 240 total, 1 block/CU (LDS-bound)

#define PITCH0  (K0_ + 8)   // LDS row pitch in halfs (+8 kills 16-way bank conflicts)
#define PITCH12 (K12_ + 8)
#define SMEM_BYTES (64 * PITCH0 * 2)   // 107,520 B (layer-0 blocks are largest)

typedef _Float16 half8 __attribute__((ext_vector_type(8)));
typedef float floatx4 __attribute__((ext_vector_type(4)));

__device__ __forceinline__ float sigm(float x) {
  return 1.f / (1.f + __expf(-x));
}
__device__ __forceinline__ float tanh_f(float x) {
  x = fminf(15.f, fmaxf(-15.f, x));
  float e = __expf(2.f * x);
  return (e - 1.f) / (e + 1.f);
}

// ---------------- prep kernels ----------------

// mel (S,U,1,NMEL,T) -> x0 (B, T, XP) fp16, transposed + zero-padded
__global__ void prep_x0(const float* __restrict__ mel, _Float16* __restrict__ x0) {
  int idx = blockIdx.x * 256 + threadIdx.x;
  if (idx >= B_ * T_ * XP_) return;
  int k = idx & (XP_ - 1);
  int t = (idx >> 6) % T_;
  int b = idx / (XP_ * T_);
  float v = (k < NMEL_) ? mel[((size_t)b * NMEL_ + k) * T_ + t] : 0.f;
  x0[idx] = (_Float16)v;
}

// Wc0 (G4, K0) = [Wih0 | 0-pad | Whh0] fp16
__global__ void prep_w0(const float* __restrict__ Wih, const float* __restrict__ Whh,
                        _Float16* __restrict__ Wc) {
  int idx = blockIdx.x * 256 + threadIdx.x;
  if (idx >= G4_ * K0_) return;
  int k = idx % K0_;
  int n = idx / K0_;
  float v = 0.f;
  if (k < NMEL_)      v = Wih[(size_t)n * NMEL_ + k];
  else if (k >= XP_)  v = Whh[(size_t)n * H_ + (k - XP_)];
  Wc[idx] = (_Float16)v;
}

// Wc (G4, K12) = [Wih | Whh] fp16
__global__ void prep_w12(const float* __restrict__ Wih, const float* __restrict__ Whh,
                         _Float16* __restrict__ Wc) {
  int idx = blockIdx.x * 256 + threadIdx.x;
  if (idx >= G4_ * K12_) return;
  int k = idx % K12_;
  int n = idx / K12_;
  float v = (k < H_) ? Wih[(size_t)n * H_ + k] : Whh[(size_t)n * H_ + (k - H_)];
  Wc[idx] = (_Float16)v;
}

__global__ void prep_bias(const float* __restrict__ bih, const float* __restrict__ bhh,
                          float* __restrict__ bias) {
  int idx = blockIdx.x * 256 + threadIdx.x;
  if (idx < G4_) bias[idx] = bih[idx] + bhh[idx];
}

// ---------------- persistent LSTM (weights LDS-resident) ----------------
// Wavefront pipeline: layer l computes t = s - l at grid-step s.
// Flags: flags[s*3+l] counts completed blocks of layer l at grid-step s.
// Block waits on (l-1, s-1), (l, s-1), (l+1, s-1) — covers true + anti deps.

template <int NT>
__device__ __forceinline__ void gemm_step(
    const _Float16* __restrict__ lw, int pitch, int K, int xK,
    const _Float16* __restrict__ xsrc, size_t xstr, const _Float16* __restrict__ hown,
    int m0, int m1, int lr, int quad, floatx4 (&acc)[2][NT]) {
  const int ko = quad * 8;

  auto aload = [&](int kc, half8* dst) {
    const bool inx = kc < xK;
    const _Float16* base = inx ? (xsrc + kc + ko) : (hown + (kc - xK) + ko);
    const size_t str = inx ? xstr : (size_t)H_;
    dst[0] = *(const half8*)(base + (size_t)(m0 + lr) * str);
    dst[1] = *(const half8*)(base + (size_t)(m1 + lr) * str);
  };
  auto bload = [&](int kc, half8* dst) {
#pragma unroll
    for (int nt = 0; nt < NT; ++nt)
      dst[nt] = *(const half8*)(lw + (size_t)(nt * 16 + lr) * pitch + kc + ko);
  };
  auto compute = [&](const half8* a, const half8* b) {
#pragma unroll
    for (int nt = 0; nt < NT; ++nt) {
      acc[0][nt] = __builtin_amdgcn_mfma_f32_16x16x32_f16(a[0], b[nt], acc[0][nt], 0, 0, 0);
      acc[1][nt] = __builtin_amdgcn_mfma_f32_16x16x32_f16(a[1], b[nt], acc[1][nt], 0, 0, 0);
    }
  };

  half8 af[2][2];
  half8 bf[2][NT];
  aload(0, af[0]);
  bload(0, bf[0]);
  for (int kc = 0; kc < K; kc += 64) {   // K/32 is even for both 832 and 1536
    if (kc + 32 < K) { aload(kc + 32, af[1]); bload(kc + 32, bf[1]); }
    compute(af[0], bf[0]);
    if (kc + 64 < K) { aload(kc + 64, af[0]); bload(kc + 64, bf[0]); }
    compute(af[1], bf[1]);
  }
}

__global__ __launch_bounds__(640)
void lstm_persist(const _Float16* __restrict__ x0,
                  const _Float16* __restrict__ Wc0, const _Float16* __restrict__ Wc1,
                  const _Float16* __restrict__ Wc2,
                  const float* __restrict__ bias, _Float16* __restrict__ hbuf,
                  int* __restrict__ flags) {
  extern __shared__ _Float16 lw[];
  const int bid = blockIdx.x;

  int layer, tile, units, K, pitch;
  const _Float16* Wsrc;
  if (bid < NB0)            { layer = 0; tile = bid;              units = 16; K = K0_;  pitch = PITCH0;  Wsrc = Wc0; }
  else if (bid < NB0+NB12)  { layer = 1; tile = bid - NB0;        units = 8;  K = K12_; pitch = PITCH12; Wsrc = Wc1; }
  else                      { layer = 2; tile = bid - NB0 - NB12; units = 8;  K = K12_; pitch = PITCH12; Wsrc = Wc2; }
  const int nrows = units * 4;
  const int j0 = tile * units;
  const int xK = (layer == 0) ? XP_ : H_;

  // ---- one-time: stage this block's weight slice into LDS (padded pitch) ----
  {
    const int nchunks = K / 8;
    for (int idx = threadIdx.x; idx < nrows * nchunks; idx += 640) {
      int r = idx / nchunks;
      int k8 = (idx % nchunks) * 8;
      int grow = (r / units) * H_ + j0 + (r % units);   // gate-major rows
      half8 v = *(const half8*)(Wsrc + (size_t)grow * K + k8);
      *(half8*)(lw + (size_t)r * pitch + k8) = v;
    }
  }
  __syncthreads();

  const int lane = threadIdx.x & 63;
  const int wv = threadIdx.x >> 6;      // 10 waves
  const int lr = lane & 15;
  const int quad = lane >> 4;
  const int m0 = wv * 32;
  const int m1 = wv * 32 + 16;
  const int j = j0 + ((units == 16) ? lr : (lr & 7));

  const float bI = bias[layer * G4_ + 0 * H_ + j];
  const float bF = bias[layer * G4_ + 1 * H_ + j];
  const float bG = bias[layer * G4_ + 2 * H_ + j];
  const float bO = bias[layer * G4_ + 3 * H_ + j];

  float cst[2][4] = {{0.f, 0.f, 0.f, 0.f}, {0.f, 0.f, 0.f, 0.f}};

  for (int t = 0; t < T_; ++t) {
    const int s = layer + t;

    // ---- wait for producers / consumers of step s-1 ----
    if (threadIdx.x == 0) {
      const int sp = s - 1;
      for (int d = -1; d <= 1; ++d) {
        int lp = layer + d;
        if (lp < 0 || lp > 2) continue;
        if (sp < lp || sp > lp + T_ - 1) continue;   // that layer not scheduled at sp
        int tgt = (lp == 0) ? NB0 : NB12;
        int spin = 0;
        while (__hip_atomic_load(&flags[sp * 3 + lp], __ATOMIC_ACQUIRE,
                                 __HIP_MEMORY_SCOPE_AGENT) < tgt) {
          __builtin_amdgcn_s_sleep(4);
          if (++spin > 1000000) break;   // bounded: fail as absmax, not a hang
        }
      }
    }
    __syncthreads();

    const int pprev = (s - 1) & 1;
    const int pcur = s & 1;
    const _Float16* xsrc;
    size_t xstr;
    if (layer == 0) { xsrc = x0 + (size_t)t * XP_; xstr = (size_t)T_ * XP_; }
    else { xsrc = hbuf + (size_t)((layer - 1) * 2 + pprev) * B_ * H_; xstr = H_; }
    const _Float16* hown = hbuf + (size_t)(layer * 2 + pprev) * B_ * H_;
    _Float16* hout = hbuf + (size_t)(layer * 2 + pcur) * B_ * H_;

    if (layer == 0) {
      floatx4 acc[2][4] = {};
      gemm_step<4>(lw, pitch, K, xK, xsrc, xstr, hown, m0, m1, lr, quad, acc);
#pragma unroll
      for (int mt = 0; mt < 2; ++mt)
#pragma unroll
        for (int r = 0; r < 4; ++r) {
          float iv = acc[mt][0][r] + bI;
          float fv = acc[mt][1][r] + bF;
          float gv = acc[mt][2][r] + bG;
          float ov = acc[mt][3][r] + bO;
          float cn = sigm(fv) * cst[mt][r] + sigm(iv) * tanh_f(gv);
          cst[mt][r] = cn;
          int m = (mt ? m1 : m0) + quad * 4 + r;
          hout[(size_t)m * H_ + j] = (_Float16)(sigm(ov) * tanh_f(cn));
        }
    } else {
      floatx4 acc[2][2] = {};
      gemm_step<2>(lw, pitch, K, xK, xsrc, xstr, hown, m0, m1, lr, quad, acc);
      // tile0 cols: i(units 0..7), f(units 0..7); tile1: g, o. xor-8 colocates gates.
#pragma unroll
      for (int mt = 0; mt < 2; ++mt)
#pragma unroll
        for (int r = 0; r < 4; ++r) {
          float t0 = acc[mt][0][r], t1 = acc[mt][1][r];
          float p0 = __shfl_xor(t0, 8, 64);
          float p1 = __shfl_xor(t1, 8, 64);
          bool lo = (lr < 8);
          float iv = (lo ? t0 : p0) + bI;
          float fv = (lo ? p0 : t0) + bF;
          float gv = (lo ? t1 : p1) + bG;
          float ov = (lo ? p1 : t1) + bO;
          float cn = sigm(fv) * cst[mt][r] + sigm(iv) * tanh_f(gv);
          cst[mt][r] = cn;
          if (lo) {
            int m = (mt ? m1 : m0) + quad * 4 + r;
            hout[(size_t)m * H_ + j] = (_Float16)(sigm(ov) * tanh_f(cn));
          }
        }
    }

    // ---- publish: syncthreads drains all waves' stores, release-add writes back L2 ----
    __syncthreads();
    if (threadIdx.x == 0)
      __hip_atomic_fetch_add(&flags[s * 3 + layer], 1, __ATOMIC_RELEASE,
                             __HIP_MEMORY_SCOPE_AGENT);
  }
}

// ---------------- projection + normalize ----------------
__global__ void dvec_kernel(const _Float16* __restrict__ hlast, const float* __restrict__ Wproj,
                            const float* __restrict__ bproj, float* __restrict__ d3) {
  const int m = blockIdx.x;
  const int d = threadIdx.x;
  const _Float16* h = hlast + (size_t)m * H_;
  const float* w = Wproj + (size_t)d * H_;
  float acc = bproj[d];
  for (int k = 0; k < H_; k++) acc += (float)h[k] * w[k];
  __shared__ float red[256];
  red[d] = acc * acc;
  __syncthreads();
  for (int off = 128; off > 0; off >>= 1) {
    if (d < off) red[d] += red[d + off];
    __syncthreads();
  }
  float nrm = sqrtf(red[0]);
  d3[(size_t)m * D_ + d] = acc / nrm;
}

// ---------------- GE2E ----------------
__device__ float block_reduce_sum(float x, float* red) {
  const int d = threadIdx.x;
  red[d] = x;
  __syncthreads();
  for (int off = 128; off > 0; off >>= 1) {
    if (d < off) red[d] += red[d + off];
    __syncthreads();
  }
  float r = red[0];
  __syncthreads();
  return r;
}

__global__ void cent_kernel(const float* __restrict__ d3, float* __restrict__ cent,
                            float* __restrict__ ncent) {
  const int sIdx = blockIdx.x;
  const int d = threadIdx.x;
  float acc = 0.f;
  for (int u = 0; u < U_; u++) acc += d3[((size_t)sIdx * U_ + u) * D_ + d];
  acc *= (1.f / U_);
  cent[sIdx * D_ + d] = acc;
  __shared__ float red[256];
  float n2 = block_reduce_sum(acc * acc, red);
  if (d == 0) ncent[sIdx] = fmaxf(sqrtf(n2), 1e-8f);
}

__global__ void ge2e_kernel(const float* __restrict__ d3, const float* __restrict__ cent,
                            const float* __restrict__ ncent, const float* __restrict__ loss_w,
                            const float* __restrict__ loss_b, float* __restrict__ accums) {
  const int p = blockIdx.x;      // (s,u) pair
  const int sIdx = p / U_;
  const int d = threadIdx.x;
  __shared__ float red[256];
  __shared__ float sims[S_];

  const float v = d3[(size_t)p * D_ + d];
  const float cs = cent[sIdx * D_ + d];
  const float pc = (cs * U_ - v) * (1.f / (U_ - 1));

  float nv2 = block_reduce_sum(v * v, red);
  float npc2 = block_reduce_sum(pc * pc, red);
  float dotp = block_reduce_sum(v * pc, red);

  const float w = loss_w[0], b = loss_b[0];
  const float na = fmaxf(sqrtf(nv2), 1e-6f);
  const float npc = fmaxf(sqrtf(npc2), 1e-6f);
  const float pos_sim = w * (dotp / (na * npc)) + b;
  const float nd = fmaxf(sqrtf(nv2), 1e-8f);

  for (int k = 0; k < S_; k++) {
    float dk = block_reduce_sum(v * cent[k * D_ + d], red);
    if (d == 0) sims[k] = w * (dk / (nd * ncent[k])) + b;
  }
  __syncthreads();
  if (d == 0) {
    float mx = -1e30f;
    for (int k = 0; k < S_; k++)
      if (k != sIdx) mx = fmaxf(mx, sims[k]);
    float se = 0.f, sn = 0.f;
    for (int k = 0; k < S_; k++)
      if (k != sIdx) { se += expf(sims[k] - mx); sn += sims[k]; }
    float lse = mx + logf(se);
    atomicAdd(&accums[0], -pos_sim + lse);
    atomicAdd(&accums[1], pos_sim);
    atomicAdd(&accums[2], sn);
  }
}

__global__ void finalize_kernel(const float* __restrict__ accums, float* __restrict__ out) {
  if (threadIdx.x == 0) {
    out[0] = accums[0] / (float)(S_ * U_);
    out[1] = accums[1] / (float)(S_ * U_);
    out[2] = accums[2] / (float)(S_ * U_ * (S_ - 1));
  }
}

// ---------------- launch ----------------
extern "C" void kernel_launch(void* const* d_in, const int* in_sizes, int n_in,
                              void* d_out, int out_size, void* d_ws, size_t ws_size,
                              hipStream_t stream) {
  const float* mel = (const float*)d_in[0];
  const float* Wih[3] = {(const float*)d_in[1], (const float*)d_in[5], (const float*)d_in[9]};
  const float* Whh[3] = {(const float*)d_in[2], (const float*)d_in[6], (const float*)d_in[10]};
  const float* bih[3] = {(const float*)d_in[3], (const float*)d_in[7], (const float*)d_in[11]};
  const float* bhh[3] = {(const float*)d_in[4], (const float*)d_in[8], (const float*)d_in[12]};
  const float* Wproj = (const float*)d_in[13];
  const float* bproj = (const float*)d_in[14];
  const float* loss_w = (const float*)d_in[15];
  const float* loss_b = (const float*)d_in[16];
  float* out = (float*)d_out;

  char* ws = (char*)d_ws;
  size_t off = 0;
  auto alloc = [&](size_t bytes) -> void* {
    void* p = ws + off;
    off = (off + bytes + 255) & ~(size_t)255;
    return p;
  };
  _Float16* x0   = (_Float16*)alloc((size_t)B_ * T_ * XP_ * 2);
  _Float16* Wc0  = (_Float16*)alloc((size_t)G4_ * K0_ * 2);
  _Float16* Wc1  = (_Float16*)alloc((size_t)G4_ * K12_ * 2);
  _Float16* Wc2  = (_Float16*)alloc((size_t)G4_ * K12_ * 2);
  float*    bias = (float*)alloc((size_t)3 * G4_ * 4);
  _Float16* hbuf = (_Float16*)alloc((size_t)6 * B_ * H_ * 2);
  float*    d3   = (float*)alloc((size_t)B_ * D_ * 4);
  float*    cent = (float*)alloc((size_t)S_ * D_ * 4);
  float*    ncent = (float*)alloc((size_t)S_ * 4);
  float*    accums = (float*)alloc(64);
  int*      flags = (int*)alloc((size_t)(T_ + 3) * 3 * 4);

  hipMemsetAsync(hbuf, 0, (size_t)6 * B_ * H_ * 2, stream);
  hipMemsetAsync(accums, 0, 64, stream);
  hipMemsetAsync(flags, 0, (size_t)(T_ + 3) * 3 * 4, stream);

  // prep
  prep_x0<<<(B_ * T_ * XP_ + 255) / 256, 256, 0, stream>>>(mel, x0);
  prep_w0<<<(G4_ * K0_ + 255) / 256, 256, 0, stream>>>(Wih[0], Whh[0], Wc0);
  prep_w12<<<(G4_ * K12_ + 255) / 256, 256, 0, stream>>>(Wih[1], Whh[1], Wc1);
  prep_w12<<<(G4_ * K12_ + 255) / 256, 256, 0, stream>>>(Wih[2], Whh[2], Wc2);
  for (int l = 0; l < 3; l++)
    prep_bias<<<(G4_ + 255) / 256, 256, 0, stream>>>(bih[l], bhh[l], bias + l * G4_);

  // persistent, weight-stationary recurrence (one cooperative launch)
  hipFuncSetAttribute((const void*)lstm_persist,
                      hipFuncAttributeMaxDynamicSharedMemorySize, SMEM_BYTES);
  void* kargs[] = {(void*)&x0, (void*)&Wc0, (void*)&Wc1, (void*)&Wc2,
                   (void*)&bias, (void*)&hbuf, (void*)&flags};
  hipLaunchCooperativeKernel((const void*)lstm_persist, dim3(NBLK), dim3(640),
                             kargs, SMEM_BYTES, stream);

  // last h of layer 2 written at grid-step 121 -> parity 1
  const _Float16* hlast = hbuf + (size_t)(2 * 2 + 1) * B_ * H_;
  dvec_kernel<<<B_, 256, 0, stream>>>(hlast, Wproj, bproj, d3);
  cent_kernel<<<S_, 256, 0, stream>>>(d3, cent, ncent);
  ge2e_kernel<<<B_, 256, 0, stream>>>(d3, cent, ncent, loss_w, loss_b, accums);
  finalize_kernel<<<1, 64, 0, stream>>>(accums, out);
}